// Round 5
// baseline (126.722 us; speedup 1.0000x reference)
//
#include <hip/hip_runtime.h>
#include <math.h>

#define B_DIM 8
#define T_DIM 1024
#define D_DIM 512
#define BT (B_DIM * T_DIM)   // 8192
#define NBLK 512             // band blocks: 8 batches x 64 tiles

typedef __bf16 bf16x8 __attribute__((ext_vector_type(8)));
typedef float floatx4 __attribute__((ext_vector_type(4)));

__device__ __forceinline__ float wave_reduce_sum(float v) {
#pragma unroll
    for (int off = 32; off > 0; off >>= 1) v += __shfl_xor(v, off, 64);
    return v;
}

// fp32 -> bf16 round-to-nearest-even (validated rounds 1-4)
__device__ __forceinline__ ushort f2bf(float x) {
    unsigned u = __float_as_uint(x);
    return (ushort)((u + 0x7fffu + ((u >> 16) & 1u)) >> 16);
}

__device__ __forceinline__ float softplus(float y) {
    return fmaxf(y, 0.0f) + log1pf(expf(-fabsf(y)));
}

// monotonic float -> uint key (order-preserving incl. negatives)
__device__ __forceinline__ unsigned fkey(float f) {
    unsigned u = __float_as_uint(f);
    return (u & 0x80000000u) ? ~u : (u | 0x80000000u);
}

// ---------------- Phase 1: normalize + convert to bf16 (high occupancy) ----
// Also zeroes the atomic-combine region (colkey/gloss/gcorr/done) so no
// separate memset dispatch is needed.
__global__ __launch_bounds__(256) void prep_kernel(
    const float* __restrict__ m, const float* __restrict__ a,
    ushort* __restrict__ mhat, ushort* __restrict__ ahat,
    unsigned* __restrict__ combine)   // [BT keys][loss][corr][done]
{
    if (blockIdx.x < 32) {
        combine[(blockIdx.x << 8) + threadIdx.x] = 0u;
    } else if (blockIdx.x == 32 && threadIdx.x < 3) {
        combine[BT + threadIdx.x] = 0u;
    }

    int wid  = blockIdx.x * 4 + (threadIdx.x >> 6);   // row in [0, 8192)
    int lane = threadIdx.x & 63;
    const float4* mr = (const float4*)(m + (size_t)wid * D_DIM);
    const float4* ar = (const float4*)(a + (size_t)wid * D_DIM);
    float4 m0 = mr[lane], m1 = mr[lane + 64];
    float4 a0 = ar[lane], a1 = ar[lane + 64];
    float sm = m0.x*m0.x + m0.y*m0.y + m0.z*m0.z + m0.w*m0.w
             + m1.x*m1.x + m1.y*m1.y + m1.z*m1.z + m1.w*m1.w;
    float sa = a0.x*a0.x + a0.y*a0.y + a0.z*a0.z + a0.w*a0.w
             + a1.x*a1.x + a1.y*a1.y + a1.z*a1.z + a1.w*a1.w;
    sm = wave_reduce_sum(sm);
    sa = wave_reduce_sum(sa);
    float im = 1.0f / fmaxf(sqrtf(sm), 1e-12f);
    float ia = 1.0f / fmaxf(sqrtf(sa), 1e-12f);
    ushort4 mo0 = { f2bf(m0.x*im), f2bf(m0.y*im), f2bf(m0.z*im), f2bf(m0.w*im) };
    ushort4 mo1 = { f2bf(m1.x*im), f2bf(m1.y*im), f2bf(m1.z*im), f2bf(m1.w*im) };
    ushort4 ao0 = { f2bf(a0.x*ia), f2bf(a0.y*ia), f2bf(a0.z*ia), f2bf(a0.w*ia) };
    ushort4 ao1 = { f2bf(a1.x*ia), f2bf(a1.y*ia), f2bf(a1.z*ia), f2bf(a1.w*ia) };
    ushort4* mw = (ushort4*)(mhat + (size_t)wid * D_DIM);
    ushort4* aw = (ushort4*)(ahat + (size_t)wid * D_DIM);
    mw[lane] = mo0; mw[lane + 64] = mo1;
    aw[lane] = ao0; aw[lane + 64] = ao1;
}

// ---------------- Phase 2: MFMA band + fused loss + atomic combine --------
// Block = (b, t0). S[i][k] = mhat_{t0+i} . ahat_{t0-16+k}, i in [0,16),
// k in [0,48). Fragments loaded directly from global (L2/L3-resident ws).
__global__ __launch_bounds__(256) void bandloss_kernel(
    const ushort* __restrict__ mhat, const ushort* __restrict__ ahat,
    const float* __restrict__ pscale, const float* __restrict__ pbias,
    unsigned* __restrict__ colkey, float* __restrict__ gloss,
    float* __restrict__ gcorr, unsigned* __restrict__ done,
    float* __restrict__ out)
{
    __shared__ float red[4][3][256];   // 12 KB k-split reduce
    __shared__ float Sbuf[16][48];     // raw scores for a2m column scan
    __shared__ float rowpos[16];
    __shared__ float shl[4];
    __shared__ int   lflag;

    int blk = blockIdx.x;
    int b   = blk >> 6;
    int t0  = (blk & 63) << 4;
    int tid  = threadIdx.x;
    int w    = tid >> 6;                  // wave id: k-split
    int lane = tid & 63;
    int mrow = lane & 15;
    int kgrp = lane >> 4;

    const ushort* Abase = mhat + ((size_t)b << 19);   // b*1024*512
    const ushort* Bbase = ahat + ((size_t)b << 19);
    int koff = w * 128 + kgrp * 8;

    const ushort* arow = Abase + (size_t)(t0 + mrow) * D_DIM + koff;
    int j0 = max(t0 - 16 + mrow, 0);
    int j1 = t0 + mrow;
    int j2 = min(t0 + 16 + mrow, T_DIM - 1);
    const ushort* br0 = Bbase + (size_t)j0 * D_DIM + koff;
    const ushort* br1 = Bbase + (size_t)j1 * D_DIM + koff;
    const ushort* br2 = Bbase + (size_t)j2 * D_DIM + koff;

    floatx4 acc0 = {0,0,0,0}, acc1 = {0,0,0,0}, acc2 = {0,0,0,0};
#pragma unroll
    for (int ks = 0; ks < 4; ++ks) {
        bf16x8 af = *(const bf16x8*)(arow + ks * 32);
        bf16x8 f0 = *(const bf16x8*)(br0 + ks * 32);
        bf16x8 f1 = *(const bf16x8*)(br1 + ks * 32);
        bf16x8 f2 = *(const bf16x8*)(br2 + ks * 32);
        acc0 = __builtin_amdgcn_mfma_f32_16x16x32_bf16(af, f0, acc0, 0, 0, 0);
        acc1 = __builtin_amdgcn_mfma_f32_16x16x32_bf16(af, f1, acc1, 0, 0, 0);
        acc2 = __builtin_amdgcn_mfma_f32_16x16x32_bf16(af, f2, acc2, 0, 0, 0);
    }

    // k-split reduce through LDS. C layout: col=lane&15, row=(lane>>4)*4+reg
#pragma unroll
    for (int r = 0; r < 4; ++r) {
        int rr = (kgrp * 4 + r) * 16 + mrow;
        red[w][0][rr] = acc0[r];
        red[w][1][rr] = acc1[r];
        red[w][2][rr] = acc2[r];
    }
    __syncthreads();

    int i  = tid >> 4;   // local row t-t0
    int cc = tid & 15;   // col within j-tile
    float s[3];
#pragma unroll
    for (int jt = 0; jt < 3; ++jt)
        s[jt] = red[0][jt][tid] + red[1][jt][tid]
              + red[2][jt][tid] + red[3][jt][tid];
#pragma unroll
    for (int jt = 0; jt < 3; ++jt)
        Sbuf[i][jt * 16 + cc] = s[jt];

    // ---- fused loss epilogue (identical masks to validated rounds 3/4) ----
    float scale = expf(pscale[0]), bias = pbias[0];
    float loss = 0.0f;
    float mmax = -1e30f, mpos = 0.0f;
#pragma unroll
    for (int jt = 0; jt < 3; ++jt) {
        int k  = jt * 16 + cc;
        int dd = k - i;                 // diag + 16
        int c  = t0 - 16 + k;
        bool cv = (c >= 0) && (c < T_DIM);
        if (cv && dd >= 0 && dd <= 32) {
            float logit = s[jt] * scale + bias;
            if (dd < 32) {              // m2a entry
                bool pos = (dd >= 12) && (dd <= 19);
                loss += softplus(pos ? -logit : logit);
                if (s[jt] > mmax) { mmax = s[jt]; mpos = pos ? 1.0f : 0.0f; }
            }
            if (dd > 0) {               // a2m entry
                bool pos = (dd >= 13) && (dd <= 20);
                loss += softplus(pos ? -logit : logit);
            }
        }
    }

    // m2a per-row argmax across 16 cc-lanes
#pragma unroll
    for (int off = 1; off < 16; off <<= 1) {
        float ov = __shfl_xor(mmax, off, 64);
        float op = __shfl_xor(mpos, off, 64);
        if (ov > mmax) { mmax = ov; mpos = op; }
    }
    if (cc == 0) rowpos[i] = mpos;

    loss = wave_reduce_sum(loss);
    if (lane == 0) shl[w] = loss;
    __syncthreads();

    // a2m per-column partial max over this block's 16 rows -> atomicMax
    if (tid < 48) {
        int k = tid;
        int c = t0 - 16 + k;
        if (c >= 0 && c < T_DIM) {
            float bv = -1e30f; float bp = 0.0f;
            int ilo = max(0, k - 32), ihi = min(16, k);
            for (int ii = ilo; ii < ihi; ++ii) {       // ascending r: first-wins
                float v = Sbuf[ii][k];
                if (v > bv) {
                    bv = v;
                    int dd = k - ii;
                    bp = (dd >= 13 && dd <= 20) ? 1.0f : 0.0f;
                }
            }
            unsigned key = (fkey(bv) & ~1u) | (bp > 0.5f ? 1u : 0u);
            atomicMax(&colkey[(b << 10) + c], key);
        }
    }
    if (tid == 0) {
        float Lb = shl[0] + shl[1] + shl[2] + shl[3];
        float Cb = 0.0f;
        for (int r = 0; r < 16; ++r) Cb += rowpos[r];
        atomicAdd(gloss, Lb);
        atomicAdd(gcorr, Cb);
    }

    // ---- last-block combine (validated round 4) ----
    __threadfence();
    __syncthreads();
    if (tid == 0) lflag = (atomicAdd(done, 1u) == (unsigned)(NBLK - 1)) ? 1 : 0;
    __syncthreads();
    if (lflag) {
        __threadfence();
        float c2 = 0.0f;
        for (int x = tid; x < BT; x += 256) {
            unsigned k = __hip_atomic_load(&colkey[x], __ATOMIC_RELAXED,
                                           __HIP_MEMORY_SCOPE_AGENT);
            c2 += (float)(k & 1u);
        }
        c2 = wave_reduce_sum(c2);
        if (lane == 0) shl[w] = c2;
        __syncthreads();
        if (tid == 0) {
            float C2 = shl[0] + shl[1] + shl[2] + shl[3];
            float L  = __hip_atomic_load(gloss, __ATOMIC_RELAXED,
                                         __HIP_MEMORY_SCOPE_AGENT);
            float C1 = __hip_atomic_load(gcorr, __ATOMIC_RELAXED,
                                         __HIP_MEMORY_SCOPE_AGENT);
            out[0] = L / 16384.0f;          // (m2a+a2m)/(2T), mean over B folded
            out[1] = (C1 + C2) / 16384.0f;  // (m2a+a2m)/(2*T*B)
        }
    }
}

extern "C" void kernel_launch(void* const* d_in, const int* in_sizes, int n_in,
                              void* d_out, int out_size, void* d_ws, size_t ws_size,
                              hipStream_t stream)
{
    const float* m  = (const float*)d_in[0];
    const float* a  = (const float*)d_in[1];
    const float* ps = (const float*)d_in[2];
    const float* pb = (const float*)d_in[3];
    float* out = (float*)d_out;

    const size_t MHAT_ELEMS = (size_t)BT * D_DIM;      // ushorts
    ushort* mhat = (ushort*)d_ws;
    ushort* ahat = mhat + MHAT_ELEMS;
    unsigned* combine = (unsigned*)(ahat + MHAT_ELEMS);  // BT keys + 3 scalars
    unsigned* colkey = combine;
    float*    gloss  = (float*)(combine + BT);
    float*    gcorr  = gloss + 1;
    unsigned* done   = (unsigned*)(gcorr + 1);

    prep_kernel<<<BT / 4, 256, 0, stream>>>(m, a, mhat, ahat, combine);
    bandloss_kernel<<<NBLK, 256, 0, stream>>>(mhat, ahat, ps, pb,
                                              colkey, gloss, gcorr, done, out);
}

// Round 6
// 102.932 us; speedup vs baseline: 1.2311x; 1.2311x over previous
//
#include <hip/hip_runtime.h>
#include <math.h>

#define B_DIM 8
#define T_DIM 1024
#define D_DIM 512
#define BT (B_DIM * T_DIM)   // 8192
#define NTILE 64             // 16-row tiles per batch
#define NBLK (B_DIM * NTILE) // 512 band blocks

typedef __bf16 bf16x8 __attribute__((ext_vector_type(8)));
typedef float floatx4 __attribute__((ext_vector_type(4)));

__device__ __forceinline__ float wave_reduce_sum(float v) {
#pragma unroll
    for (int off = 32; off > 0; off >>= 1) v += __shfl_xor(v, off, 64);
    return v;
}

// fp32 -> bf16 round-to-nearest-even (validated rounds 1-5)
__device__ __forceinline__ ushort f2bf(float x) {
    unsigned u = __float_as_uint(x);
    return (ushort)((u + 0x7fffu + ((u >> 16) & 1u)) >> 16);
}

__device__ __forceinline__ float softplus(float y) {
    return fmaxf(y, 0.0f) + log1pf(expf(-fabsf(y)));
}

// build a bf16x8 A/B fragment from 8 consecutive raw fp32 elements
__device__ __forceinline__ bf16x8 load_frag(const float* __restrict__ p) {
    float4 x = *(const float4*)p;
    float4 y = *(const float4*)(p + 4);
    union { ushort u[8]; bf16x8 v; } r;
    r.u[0] = f2bf(x.x); r.u[1] = f2bf(x.y); r.u[2] = f2bf(x.z); r.u[3] = f2bf(x.w);
    r.u[4] = f2bf(y.x); r.u[5] = f2bf(y.y); r.u[6] = f2bf(y.z); r.u[7] = f2bf(y.w);
    return r.v;
}

// ---------------- Phase 1: inverse norms only (high occupancy) ----------
__global__ __launch_bounds__(256) void norm_kernel(
    const float* __restrict__ m, const float* __restrict__ a,
    float* __restrict__ invm, float* __restrict__ inva)
{
    int wid  = blockIdx.x * 4 + (threadIdx.x >> 6);   // row in [0, 8192)
    int lane = threadIdx.x & 63;
    const float4* mr = (const float4*)(m + (size_t)wid * D_DIM);
    const float4* ar = (const float4*)(a + (size_t)wid * D_DIM);
    float4 m0 = mr[lane], m1 = mr[lane + 64];
    float4 a0 = ar[lane], a1 = ar[lane + 64];
    float sm = m0.x*m0.x + m0.y*m0.y + m0.z*m0.z + m0.w*m0.w
             + m1.x*m1.x + m1.y*m1.y + m1.z*m1.z + m1.w*m1.w;
    float sa = a0.x*a0.x + a0.y*a0.y + a0.z*a0.z + a0.w*a0.w
             + a1.x*a1.x + a1.y*a1.y + a1.z*a1.z + a1.w*a1.w;
    sm = wave_reduce_sum(sm);
    sa = wave_reduce_sum(sa);
    if (lane == 0) {
        invm[wid] = 1.0f / fmaxf(sqrtf(sm), 1e-12f);
        inva[wid] = 1.0f / fmaxf(sqrtf(sa), 1e-12f);
    }
}

// ---------------- Phase 2: MFMA band on raw fp32 + fused loss -----------
// Block = (b, t0). S[i][k] = m_{t0+i} . a_{t0-16+k} (RAW dot), i in [0,16),
// k in [0,48). logit = S * invm[t] * inva[c] * scale + bias.
__global__ __launch_bounds__(256) void bandloss_kernel(
    const float* __restrict__ m, const float* __restrict__ a,
    const float* __restrict__ invm, const float* __restrict__ inva,
    const float* __restrict__ pscale, const float* __restrict__ pbias,
    float2* __restrict__ pm,
    float* __restrict__ part_loss, float* __restrict__ part_corr)
{
    __shared__ float red[4][3][256];   // 12 KB k-split reduce
    __shared__ float Sbuf[16][48];     // raw scores for a2m column scan
    __shared__ float rowpos[16];
    __shared__ float shl[4];

    int blk = blockIdx.x;
    int b   = blk >> 6;
    int t0  = (blk & 63) << 4;
    int tid  = threadIdx.x;
    int w    = tid >> 6;                  // wave id: k-split
    int lane = tid & 63;
    int mrow = lane & 15;
    int kgrp = lane >> 4;

    const float* mb = m + ((size_t)b << 19);   // b*1024*512
    const float* ab = a + ((size_t)b << 19);
    int koff = w * 128 + kgrp * 8;

    const float* arow = mb + (size_t)(t0 + mrow) * D_DIM + koff;
    int j0 = max(t0 - 16 + mrow, 0);
    int j1 = t0 + mrow;
    int j2 = min(t0 + 16 + mrow, T_DIM - 1);
    const float* br0 = ab + (size_t)j0 * D_DIM + koff;
    const float* br1 = ab + (size_t)j1 * D_DIM + koff;
    const float* br2 = ab + (size_t)j2 * D_DIM + koff;

    floatx4 acc0 = {0,0,0,0}, acc1 = {0,0,0,0}, acc2 = {0,0,0,0};
#pragma unroll
    for (int ks = 0; ks < 4; ++ks) {
        bf16x8 af = load_frag(arow + ks * 32);
        bf16x8 f0 = load_frag(br0 + ks * 32);
        bf16x8 f1 = load_frag(br1 + ks * 32);
        bf16x8 f2 = load_frag(br2 + ks * 32);
        acc0 = __builtin_amdgcn_mfma_f32_16x16x32_bf16(af, f0, acc0, 0, 0, 0);
        acc1 = __builtin_amdgcn_mfma_f32_16x16x32_bf16(af, f1, acc1, 0, 0, 0);
        acc2 = __builtin_amdgcn_mfma_f32_16x16x32_bf16(af, f2, acc2, 0, 0, 0);
    }

    // k-split reduce through LDS. C layout: col=lane&15, row=(lane>>4)*4+reg
#pragma unroll
    for (int r = 0; r < 4; ++r) {
        int rr = (kgrp * 4 + r) * 16 + mrow;
        red[w][0][rr] = acc0[r];
        red[w][1][rr] = acc1[r];
        red[w][2][rr] = acc2[r];
    }
    __syncthreads();

    int i  = tid >> 4;   // local row t-t0
    int cc = tid & 15;   // col within j-tile
    float s[3];
#pragma unroll
    for (int jt = 0; jt < 3; ++jt)
        s[jt] = red[0][jt][tid] + red[1][jt][tid]
              + red[2][jt][tid] + red[3][jt][tid];
#pragma unroll
    for (int jt = 0; jt < 3; ++jt)
        Sbuf[i][jt * 16 + cc] = s[jt];

    // ---- fused loss epilogue (masks identical to validated rounds 3-5) ----
    float scale = expf(pscale[0]), bias = pbias[0];
    float im_i  = invm[(b << 10) + t0 + i];    // this thread's row inv-norm
    float loss = 0.0f;
    float mmax = -1e30f, mpos = 0.0f;          // m2a argmax key: s * inva[c]
#pragma unroll
    for (int jt = 0; jt < 3; ++jt) {
        int k  = jt * 16 + cc;
        int dd = k - i;                 // diag + 16
        int c  = t0 - 16 + k;
        bool cv = (c >= 0) && (c < T_DIM);
        if (cv && dd >= 0 && dd <= 32) {
            float ia_c  = inva[(b << 10) + c];
            float sv    = s[jt] * ia_c;                    // s * inva[c]
            float logit = sv * im_i * scale + bias;
            if (dd < 32) {              // m2a entry
                bool pos = (dd >= 12) && (dd <= 19);
                loss += softplus(pos ? -logit : logit);
                if (sv > mmax) { mmax = sv; mpos = pos ? 1.0f : 0.0f; }
            }
            if (dd > 0) {               // a2m entry
                bool pos = (dd >= 13) && (dd <= 20);
                loss += softplus(pos ? -logit : logit);
            }
        }
    }

    // m2a per-row argmax across 16 cc-lanes
#pragma unroll
    for (int off = 1; off < 16; off <<= 1) {
        float ov = __shfl_xor(mmax, off, 64);
        float op = __shfl_xor(mpos, off, 64);
        if (ov > mmax) { mmax = ov; mpos = op; }
    }
    if (cc == 0) rowpos[i] = mpos;

    loss = wave_reduce_sum(loss);
    if (lane == 0) shl[w] = loss;
    __syncthreads();

    // a2m per-column partial max over this block's 16 rows (key: s*invm[r])
    if (tid < 48) {
        int k = tid;
        int c = t0 - 16 + k;
        float bv = -1e30f, bp = 0.0f;
        if (c >= 0 && c < T_DIM) {
            int ilo = max(0, k - 32), ihi = min(16, k);
            for (int ii = ilo; ii < ihi; ++ii) {       // ascending r: first-wins
                float v = Sbuf[ii][k] * invm[(b << 10) + t0 + ii];
                if (v > bv) {
                    bv = v;
                    int dd = k - ii;
                    bp = (dd >= 13 && dd <= 20) ? 1.0f : 0.0f;
                }
            }
        }
        pm[blk * 48 + k] = make_float2(bv, bp);
    }
    if (tid == 0) {
        float cs = 0.0f;
        for (int r = 0; r < 16; ++r) cs += rowpos[r];
        part_loss[blk] = shl[0] + shl[1] + shl[2] + shl[3];
        part_corr[blk] = cs;
    }
}

// ---------------- Phase 3: combine partials -> out (validated round 3) ----
__global__ __launch_bounds__(1024) void final2_kernel(
    const float2* __restrict__ pm,
    const float* __restrict__ part_loss, const float* __restrict__ part_corr,
    float* __restrict__ out)
{
    int tid = threadIdx.x;
    float corr = 0.0f, loss = 0.0f;

    // a2m argmax: combine <=3 block partials per column
    for (int x = tid; x < BT; x += 1024) {
        int b = x >> 10, c = x & 1023;
        int tc = c >> 4;
        float bv = -1e30f, bp = 0.0f;
#pragma unroll
        for (int dp = -1; dp <= 1; ++dp) {   // ascending r
            int p = tc + dp;
            if (p < 0 || p >= NTILE) continue;
            int k = c - (p << 4) + 16;
            float2 v = pm[((b << 6) + p) * 48 + k];
            if (v.x > bv) { bv = v.x; bp = v.y; }
        }
        corr += bp;
    }
    if (tid < NBLK) {
        loss = part_loss[tid];
        corr += part_corr[tid];
    }

    loss = wave_reduce_sum(loss);
    corr = wave_reduce_sum(corr);
    __shared__ float shl[16], shc[16];
    int wv = tid >> 6, lane = tid & 63;
    if (lane == 0) { shl[wv] = loss; shc[wv] = corr; }
    __syncthreads();
    if (tid == 0) {
        float L = 0.0f, C = 0.0f;
#pragma unroll
        for (int r = 0; r < 16; ++r) { L += shl[r]; C += shc[r]; }
        out[0] = L / 16384.0f;   // (m2a+a2m)/(2T), mean over B folded in
        out[1] = C / 16384.0f;   // (m2a+a2m)/(2*T*B)
    }
}

extern "C" void kernel_launch(void* const* d_in, const int* in_sizes, int n_in,
                              void* d_out, int out_size, void* d_ws, size_t ws_size,
                              hipStream_t stream)
{
    const float* m  = (const float*)d_in[0];
    const float* a  = (const float*)d_in[1];
    const float* ps = (const float*)d_in[2];
    const float* pb = (const float*)d_in[3];
    float* out = (float*)d_out;

    float*  ws        = (float*)d_ws;
    float*  invm      = ws;                        // 8192
    float*  inva      = ws + BT;                   // 8192
    float2* pm        = (float2*)(ws + 2 * BT);    // 512*48 float2
    float*  part_loss = (float*)(pm + NBLK * 48);  // 512
    float*  part_corr = part_loss + NBLK;          // 512

    norm_kernel<<<BT / 4, 256, 0, stream>>>(m, a, invm, inva);
    bandloss_kernel<<<NBLK, 256, 0, stream>>>(m, a, invm, inva, ps, pb,
                                              pm, part_loss, part_corr);
    final2_kernel<<<1, 1024, 0, stream>>>(pm, part_loss, part_corr, out);
}

// Round 7
// 93.050 us; speedup vs baseline: 1.3619x; 1.1062x over previous
//
#include <hip/hip_runtime.h>
#include <hip/hip_bf16.h>
#include <math.h>

#define B_DIM 8
#define T_DIM 1024
#define D_DIM 512
#define BT (B_DIM * T_DIM)   // 8192
#define NBLK 512             // 8 batches x 64 tiles of 16 queries

typedef __bf16 bf16x8 __attribute__((ext_vector_type(8)));
typedef float floatx4 __attribute__((ext_vector_type(4)));

__device__ __forceinline__ float wave_reduce_sum(float v) {
#pragma unroll
    for (int off = 32; off > 0; off >>= 1) v += __shfl_xor(v, off, 64);
    return v;
}

__device__ __forceinline__ float softplus(float y) {
    return fmaxf(y, 0.0f) + log1pf(expf(-fabsf(y)));
}

// 8 fp32 -> bf16x8 fragment, RNE (HIP API; same rounding as validated f2bf)
__device__ __forceinline__ bf16x8 cvt8(float4 x, float4 y) {
    union { ushort u[8]; bf16x8 v; } r;
    __hip_bfloat162 h0 = __float22bfloat162_rn(make_float2(x.x, x.y));
    __hip_bfloat162 h1 = __float22bfloat162_rn(make_float2(x.z, x.w));
    __hip_bfloat162 h2 = __float22bfloat162_rn(make_float2(y.x, y.y));
    __hip_bfloat162 h3 = __float22bfloat162_rn(make_float2(y.z, y.w));
    ushort2 p0 = *(ushort2*)&h0, p1 = *(ushort2*)&h1;
    ushort2 p2 = *(ushort2*)&h2, p3 = *(ushort2*)&h3;
    r.u[0] = p0.x; r.u[1] = p0.y; r.u[2] = p1.x; r.u[3] = p1.y;
    r.u[4] = p2.x; r.u[5] = p2.y; r.u[6] = p3.x; r.u[7] = p3.y;
    return r.v;
}

// One block = (b, t0): computes S[u][v] = m_{t0-16+u} . a_{t0-16+v} (raw fp32
// dots via bf16 MFMA), u,v in [0,48). Owns COMPLETE m2a windows for rows
// u in [16,32) and complete a2m windows for cols v in [16,32). Norms computed
// in-block from the fp32 fragments. Writes only (loss, corr) partials.
__global__ __launch_bounds__(256, 2) void bigband_kernel(
    const float* __restrict__ m, const float* __restrict__ a,
    const float* __restrict__ pscale, const float* __restrict__ pbias,
    float* __restrict__ part_loss, float* __restrict__ part_corr)
{
    __shared__ float red[4][9][272];   // k-split reduce, row stride 17
    __shared__ float Sbuf[48][49];     // summed scores (padded)
    __shared__ float red2[4][6][16];   // per-wave row sumsq partials
    __shared__ float norms[6][16];     // inv-norms: slots 0-2 m, 3-5 a
    __shared__ float rowpos[16], colpos[16], shl[4];

    int blk = blockIdx.x;
    int b   = blk >> 6;
    int t0  = (blk & 63) << 4;
    int tid  = threadIdx.x;
    int w    = tid >> 6;               // wave id: k-split (128 elems each)
    int lane = tid & 63;
    int mrow = lane & 15;
    int kgrp = lane >> 4;
    int koff = w * 128 + kgrp * 8;

    const float* mb = m + ((size_t)b << 19);   // b*1024*512
    const float* ab = a + ((size_t)b << 19);

    const float* mp[3]; const float* ap[3];
#pragma unroll
    for (int s = 0; s < 3; ++s) {
        int r = t0 - 16 + s * 16 + mrow;       // clamped; masked in epilogue
        r = min(max(r, 0), T_DIM - 1);
        mp[s] = mb + (size_t)r * D_DIM + koff;
        ap[s] = ab + (size_t)r * D_DIM + koff;
    }

    floatx4 acc[3][3];
#pragma unroll
    for (int ti = 0; ti < 3; ++ti)
#pragma unroll
        for (int tj = 0; tj < 3; ++tj) acc[ti][tj] = (floatx4){0.f,0.f,0.f,0.f};
    float ssm[3] = {0.f,0.f,0.f}, ssa[3] = {0.f,0.f,0.f};

#pragma unroll
    for (int ks = 0; ks < 4; ++ks) {
        bf16x8 am[3], av[3];
#pragma unroll
        for (int s = 0; s < 3; ++s) {
            float4 x = *(const float4*)(mp[s] + ks * 32);
            float4 y = *(const float4*)(mp[s] + ks * 32 + 4);
            ssm[s] += x.x*x.x + x.y*x.y + x.z*x.z + x.w*x.w
                    + y.x*y.x + y.y*y.y + y.z*y.z + y.w*y.w;
            am[s] = cvt8(x, y);
            float4 u = *(const float4*)(ap[s] + ks * 32);
            float4 v = *(const float4*)(ap[s] + ks * 32 + 4);
            ssa[s] += u.x*u.x + u.y*u.y + u.z*u.z + u.w*u.w
                    + v.x*v.x + v.y*v.y + v.z*v.z + v.w*v.w;
            av[s] = cvt8(u, v);
        }
#pragma unroll
        for (int ti = 0; ti < 3; ++ti)
#pragma unroll
            for (int tj = 0; tj < 3; ++tj)
                acc[ti][tj] = __builtin_amdgcn_mfma_f32_16x16x32_bf16(
                    am[ti], av[tj], acc[ti][tj], 0, 0, 0);
    }

    // reduce sumsq across the 4 kgrp lanes of each row (xor 16, 32)
#pragma unroll
    for (int off = 16; off <= 32; off <<= 1) {
#pragma unroll
        for (int s = 0; s < 3; ++s) {
            ssm[s] += __shfl_xor(ssm[s], off, 64);
            ssa[s] += __shfl_xor(ssa[s], off, 64);
        }
    }
    if (kgrp == 0) {
#pragma unroll
        for (int s = 0; s < 3; ++s) {
            red2[w][s][mrow]     = ssm[s];
            red2[w][3 + s][mrow] = ssa[s];
        }
    }
    // k-split score partials. C layout: col=lane&15, row=(lane>>4)*4+reg
#pragma unroll
    for (int ti = 0; ti < 3; ++ti)
#pragma unroll
        for (int tj = 0; tj < 3; ++tj)
#pragma unroll
            for (int r = 0; r < 4; ++r)
                red[w][ti * 3 + tj][(kgrp * 4 + r) * 17 + mrow] = acc[ti][tj][r];
    __syncthreads();

    if (tid < 96) {
        int slot = tid >> 4, mr = tid & 15;
        float ss = red2[0][slot][mr] + red2[1][slot][mr]
                 + red2[2][slot][mr] + red2[3][slot][mr];
        norms[slot][mr] = 1.0f / fmaxf(sqrtf(ss), 1e-12f);
    }
    int rho = tid >> 4, kap = tid & 15;    // within-tile (row, col)
#pragma unroll
    for (int ti = 0; ti < 3; ++ti)
#pragma unroll
        for (int tj = 0; tj < 3; ++tj) {
            int tt = ti * 3 + tj;
            float s4 = red[0][tt][rho * 17 + kap] + red[1][tt][rho * 17 + kap]
                     + red[2][tt][rho * 17 + kap] + red[3][tt][rho * 17 + kap];
            Sbuf[ti * 16 + rho][tj * 16 + kap] = s4;
        }
    __syncthreads();

    // ---- epilogue: thread (i=rho, cc=kap) ----
    float scale = expf(pscale[0]), bias = pbias[0];
    int i = rho, cc = kap;
    float loss = 0.0f;

    // m2a: query t = t0+i (tile row u = 16+i), cols v = tj*16+cc
    {
        float im_u = norms[1][i];
        float mmax = -1e30f, mpos = 0.0f;
#pragma unroll
        for (int tj = 0; tj < 3; ++tj) {
            int v  = tj * 16 + cc;
            int dd = v - i;                    // c - t + 16
            int c  = t0 - 16 + v;
            if (dd >= 0 && dd < 32 && c >= 0 && c < T_DIM) {
                float sv = Sbuf[16 + i][v] * norms[3 + tj][cc];  // s*inva[c]
                float logit = sv * im_u * scale + bias;
                bool pos = (dd >= 12) && (dd <= 19);
                loss += softplus(pos ? -logit : logit);
                if (sv > mmax) { mmax = sv; mpos = pos ? 1.0f : 0.0f; }
            }
        }
#pragma unroll
        for (int off = 1; off < 16; off <<= 1) {
            float ov = __shfl_xor(mmax, off, 64);
            float op = __shfl_xor(mpos, off, 64);
            if (ov > mmax) { mmax = ov; mpos = op; }
        }
        if (cc == 0) rowpos[i] = mpos;
    }

    // a2m: query t = t0+i (tile col v = 16+i), rows u2 = tj*16+cc
    {
        float ia_v = norms[4][i];
        float amax = -1e30f, apos = 0.0f;
#pragma unroll
        for (int tj = 0; tj < 3; ++tj) {
            int u2 = tj * 16 + cc;
            int ee = u2 - i;                   // r - t + 16
            int r  = t0 - 16 + u2;
            if (ee >= 0 && ee < 32 && r >= 0 && r < T_DIM) {
                float sv = Sbuf[u2][16 + i] * norms[tj][cc];     // s*invm[r]
                float logit = sv * ia_v * scale + bias;
                bool pos = (ee >= 12) && (ee <= 19);
                loss += softplus(pos ? -logit : logit);
                if (sv > amax) { amax = sv; apos = pos ? 1.0f : 0.0f; }
            }
        }
#pragma unroll
        for (int off = 1; off < 16; off <<= 1) {
            float ov = __shfl_xor(amax, off, 64);
            float op = __shfl_xor(apos, off, 64);
            if (ov > amax) { amax = ov; apos = op; }
        }
        if (cc == 0) colpos[i] = apos;
    }

    loss = wave_reduce_sum(loss);
    if (lane == 0) shl[w] = loss;
    __syncthreads();
    if (tid == 0) {
        float C = 0.0f;
#pragma unroll
        for (int r = 0; r < 16; ++r) C += rowpos[r] + colpos[r];
        part_loss[blk] = shl[0] + shl[1] + shl[2] + shl[3];
        part_corr[blk] = C;
    }
}

__global__ __launch_bounds__(256) void finalsum_kernel(
    const float* __restrict__ part_loss, const float* __restrict__ part_corr,
    float* __restrict__ out)
{
    int tid = threadIdx.x;
    float l = part_loss[tid] + part_loss[tid + 256];
    float c = part_corr[tid] + part_corr[tid + 256];
    l = wave_reduce_sum(l);
    c = wave_reduce_sum(c);
    __shared__ float shl[4], shc[4];
    int w = tid >> 6, lane = tid & 63;
    if (lane == 0) { shl[w] = l; shc[w] = c; }
    __syncthreads();
    if (tid == 0) {
        out[0] = (shl[0] + shl[1] + shl[2] + shl[3]) / 16384.0f;
        out[1] = (shc[0] + shc[1] + shc[2] + shc[3]) / 16384.0f;
    }
}

extern "C" void kernel_launch(void* const* d_in, const int* in_sizes, int n_in,
                              void* d_out, int out_size, void* d_ws, size_t ws_size,
                              hipStream_t stream)
{
    const float* m  = (const float*)d_in[0];
    const float* a  = (const float*)d_in[1];
    const float* ps = (const float*)d_in[2];
    const float* pb = (const float*)d_in[3];
    float* out = (float*)d_out;

    float* part_loss = (float*)d_ws;          // 512
    float* part_corr = part_loss + NBLK;      // 512

    bigband_kernel<<<NBLK, 256, 0, stream>>>(m, a, ps, pb, part_loss, part_corr);
    finalsum_kernel<<<1, 256, 0, stream>>>(part_loss, part_corr, out);
}